// Round 12
// baseline (183.328 us; speedup 1.0000x reference)
//
#include <hip/hip_runtime.h>
#include <hip/hip_bf16.h>

#define K_CODES 512
#define CDIM    256
#define HW      1024
#define NBATCH  64
#define SZ      260   // validated LDS stride

typedef float  f32x16 __attribute__((ext_vector_type(16)));
typedef short  bf16x8 __attribute__((ext_vector_type(8)));

typedef __attribute__((address_space(1))) const unsigned int gld_src_t;
typedef __attribute__((address_space(3))) unsigned int       gld_dst_t;

__device__ __forceinline__ unsigned short f2bf(float x) {
    unsigned u = __float_as_uint(x);
    unsigned r = (u + 0x7FFFu + ((u >> 16) & 1u)) >> 16;   // RNE
    return (unsigned short)r;
}

// ---------------- Fused setup: zt+zn (blocks 0..1023), prep (1024..1151), cbT (1152..1183) ----------------
__global__ __launch_bounds__(256) void vq_setup(const float* __restrict__ z,
                                                const float* __restrict__ cb,
                                                float* __restrict__ zn_out,
                                                float* __restrict__ zt_out,
                                                float* __restrict__ enorm,
                                                unsigned short* __restrict__ cb16,
                                                float* __restrict__ cbT,
                                                unsigned* __restrict__ ctr) {
    __shared__ __align__(16) char sm[66560];
    const int t   = threadIdx.x;
    const int bid = blockIdx.x;

    if (bid < 1024) {
        // ---- z transpose + row norms (bit-identical validated staging/chain)
        float (*zs)[SZ] = reinterpret_cast<float(*)[SZ]>(sm);
        const int r0 = bid * 64;
        const int b  = r0 >> 10;
        const int n0 = r0 & 1023;
        const float* zb = z + (size_t)b * CDIM * HW;
#pragma unroll
        for (int p = 0; p < 16; ++p) {
            int lin = p * 256 + t;
            int c   = lin >> 4;
            int i0  = (lin & 15) << 2;
            float4 v = *reinterpret_cast<const float4*>(zb + (size_t)c * HW + n0 + i0);
            zs[i0 + 0][c] = v.x; zs[i0 + 1][c] = v.y;
            zs[i0 + 2][c] = v.z; zs[i0 + 3][c] = v.w;
        }
        __syncthreads();
        if (t < 64) {
            float s0 = 0.f, s1 = 0.f, s2 = 0.f, s3 = 0.f;
            for (int c = 0; c < CDIM; c += 4) {
                float4 v = *reinterpret_cast<const float4*>(&zs[t][c]);
                s0 += v.x * v.x; s1 += v.y * v.y; s2 += v.z * v.z; s3 += v.w * v.w;
            }
            zn_out[r0 + t] = (s0 + s1) + (s2 + s3);
        }
#pragma unroll
        for (int p = 0; p < 16; ++p) {
            int f   = p * 256 + t;
            int row = f >> 6;
            int c4  = (f & 63) << 2;
            float4 v = *reinterpret_cast<const float4*>(&zs[row][c4]);
            *reinterpret_cast<float4*>(zt_out + (((size_t)(r0 + row)) << 8) + c4) = v;
        }
    } else if (bid < 1152) {
        // ---- prep: 4 codes/block, one 64-lane wave-group per code (validated butterfly)
        if (bid == 1024 && t < 4) ctr[t] = 0;
        int code = ((bid - 1024) << 2) + (t >> 6);
        int l = t & 63;
        float4 v = *reinterpret_cast<const float4*>(cb + (size_t)code * CDIM + l * 4);
        float s = (v.x * v.x + v.y * v.y) + (v.z * v.z + v.w * v.w);
#pragma unroll
        for (int off = 1; off < 64; off <<= 1) s += __shfl_xor(s, off, 64);
        if (l == 0) enorm[code] = s;
        ushort4 o;
        o.x = f2bf(v.x); o.y = f2bf(v.y); o.z = f2bf(v.z); o.w = f2bf(v.w);
        *reinterpret_cast<ushort4*>(cb16 + (size_t)code * CDIM + l * 4) = o;
    } else {
        // ---- cbT: codebook transpose tile (identical to validated vq_cbt)
        float (*st)[65] = reinterpret_cast<float(*)[65]>(sm);
        const int bb = bid - 1152;
        const int k0 = (bb >> 2) << 6;
        const int c0 = (bb & 3) << 6;
#pragma unroll
        for (int q = 0; q < 4; ++q) {
            int lin = (q << 8) + t;
            int kr  = lin >> 4;
            int cc  = (lin & 15) << 2;
            float4 v = *reinterpret_cast<const float4*>(cb + (size_t)(k0 + kr) * CDIM + c0 + cc);
            st[kr][cc + 0] = v.x; st[kr][cc + 1] = v.y;
            st[kr][cc + 2] = v.z; st[kr][cc + 3] = v.w;
        }
        __syncthreads();
#pragma unroll
        for (int q = 0; q < 4; ++q) {
            int lin = (q << 8) + t;
            int cr  = lin >> 4;
            int kk  = (lin & 15) << 2;
            float4 v = make_float4(st[kk + 0][cr], st[kk + 1][cr],
                                   st[kk + 2][cr], st[kk + 3][cr]);
            *reinterpret_cast<float4*>(cbT + (size_t)(c0 + cr) * K_CODES + k0 + kk) = v;
        }
    }
}

// ---------------- Pass 1: single-sweep MFMA filter, u8-delta value store, O(cand) emission ----------------
// 128 rows/block, 256 thr (4 waves x 32 rows). 16 phases of 32 codes, async es ring.
// Per phase: pm (f32) + 16 conservative u8 deltas q=min(255,floor((pm-v)*2048)) in 4 u32.
// Candidate emission test q <= (pm-thr)*2048+1 provably includes all v >= thr.
__global__ __launch_bounds__(256, 2) void vq_pass1(const float* __restrict__ z,
                                                   const unsigned short* __restrict__ cb16,
                                                   unsigned short* __restrict__ codes_out,
                                                   int* __restrict__ idx_out,
                                                   unsigned* __restrict__ mlist,
                                                   unsigned* __restrict__ oflist,
                                                   unsigned* __restrict__ ctr) {
    __shared__ __align__(16) char smem[70144];
    unsigned short* zs    = (unsigned short*)smem;            // 64KB transient
    unsigned*       zsw   = (unsigned*)smem;
    unsigned short* es    = (unsigned short*)smem;            // reuse: 4 x 16KB ring
    unsigned short* candl = (unsigned short*)(smem + 65536);  // 128*16 u16
    unsigned*       cntl  = (unsigned*)(smem + 69632);        // 128 u32

    const int t = threadIdx.x;
    const int l = t & 63, w = t >> 6;          // 4 waves
    const int r0 = blockIdx.x << 7;            // 128 rows/block
    const int b  = r0 >> 10, n0 = r0 & 1023;
    const float* zb = z + (size_t)b * (CDIM * HW);

    // ---- stage z: transpose + bf16 (identical bit-path to validated rounds)
#pragma unroll
    for (int p = 0; p < 16; ++p) {
        int lin = (p << 8) + t;
        int c2  = lin >> 5;          // 0..127 (k-pairs)
        int iq  = lin & 31;          // 0..31  (row-quads)
        const float* g0 = zb + (size_t)(2 * c2) * HW + n0 + (iq << 2);
        float4 a  = *reinterpret_cast<const float4*>(g0);
        float4 bb = *reinterpret_cast<const float4*>(g0 + HW);
        int up = (((c2 >> 2) ^ (iq & 7)) << 2) + (c2 & 3);
        const float* ap = &a.x; const float* bp = &bb.x;
#pragma unroll
        for (int j = 0; j < 4; ++j) {
            unsigned pk = (unsigned)f2bf(ap[j]) | ((unsigned)f2bf(bp[j]) << 16);
            zsw[((iq << 2) + j) * 128 + up] = pk;
        }
    }
    __syncthreads();

    // ---- B-frags (z rows) into registers (identical to validated rounds)
    const int lrow = l & 31, lh = l >> 5;
    const int lf  = (lrow >> 2) & 7;
    const int row = (w << 5) + lrow;           // 0..127
    bf16x8 zf[16];
#pragma unroll
    for (int s = 0; s < 16; ++s) {
        int u = (2 * s + lh) ^ lf;
        zf[s] = *reinterpret_cast<const bf16x8*>(&zs[row * 256 + (u << 3)]);
    }
    float sa = 0.f;
#pragma unroll
    for (int s = 0; s < 16; ++s)
#pragma unroll
        for (int j = 0; j < 8; ++j)
            sa += fabsf(__uint_as_float(((unsigned)(unsigned short)zf[s][j]) << 16));
    sa += __shfl_xor(sa, 32, 64);

    __syncthreads();   // all zs reads done -> es ring may reuse region
    if (t < 128) cntl[t] = 0;

    // ---- async es stager: wave w fills chunks w*4..w*4+3 (1KB each) of a phase
    const int lq = l & 31, lhh = l >> 5;
    auto ISSUE = [&](int ph) {
#pragma unroll
        for (int j = 0; j < 4; ++j) {
            int chunk = (w << 2) + j;
            int lc    = (chunk << 1) + lhh;        // local code 0..31
            int su    = (lq - lc) & 31;            // pre-rotated source unit
            const unsigned short* gp = cb16 + (((size_t)((ph << 5) + lc)) << 8) + (su << 3);
            char* lp = smem + (((ph & 3) << 14) + (chunk << 10));
            __builtin_amdgcn_global_load_lds((gld_src_t*)gp, (gld_dst_t*)lp, 16, 0, 0);
        }
    };

    ISSUE(0); ISSUE(1);
    asm volatile("s_waitcnt vmcnt(4)" ::: "memory");
    __builtin_amdgcn_s_barrier();   // also publishes cntl zeroing

    float runmax = -3.4e38f;
    float pmv[16];                   // per-phase max (static idx after unroll)
    unsigned dw[64];                 // 16 phases x 4 u8-packed delta words

#pragma unroll
    for (int p = 0; p < 16; ++p) {
        if (p + 2 < 16) ISSUE(p + 2);
        if (p >= 1) {
            if (p < 14)       asm volatile("s_waitcnt vmcnt(8)" ::: "memory");
            else if (p == 14) asm volatile("s_waitcnt vmcnt(4)" ::: "memory");
            else              asm volatile("s_waitcnt vmcnt(0)" ::: "memory");
            __builtin_amdgcn_s_barrier();
        }
        const unsigned short* eb = es + ((p & 3) << 13);

        f32x16 accA = {0.f,0.f,0.f,0.f,0.f,0.f,0.f,0.f,0.f,0.f,0.f,0.f,0.f,0.f,0.f,0.f};
        f32x16 accB = accA;
#pragma unroll
        for (int s = 0; s < 16; s += 2) {
            int u0 = (2 * s + lh + lrow) & 31;
            int u1 = (2 * s + 2 + lh + lrow) & 31;
            bf16x8 a0 = *reinterpret_cast<const bf16x8*>(&eb[(lrow << 8) + (u0 << 3)]);
            bf16x8 a1 = *reinterpret_cast<const bf16x8*>(&eb[(lrow << 8) + (u1 << 3)]);
            accA = __builtin_amdgcn_mfma_f32_32x32x16_bf16(a0, zf[s],     accA, 0, 0, 0);
            accB = __builtin_amdgcn_mfma_f32_32x32x16_bf16(a1, zf[s + 1], accB, 0, 0, 0);
        }

        float v[16];
#pragma unroll
        for (int i = 0; i < 16; ++i) v[i] = accA[i] + accB[i];
        float m01 = fmaxf(fmaxf(v[0], v[1]), fmaxf(v[2], v[3]));
        float m23 = fmaxf(fmaxf(v[4], v[5]), fmaxf(v[6], v[7]));
        float m45 = fmaxf(fmaxf(v[8], v[9]), fmaxf(v[10], v[11]));
        float m67 = fmaxf(fmaxf(v[12], v[13]), fmaxf(v[14], v[15]));
        float pm  = fmaxf(fmaxf(m01, m23), fmaxf(m45, m67));
        pmv[p] = pm;
        float pm2048 = pm * 2048.0f;
#pragma unroll
        for (int w4 = 0; w4 < 4; ++w4) {
            unsigned wd = 0;
#pragma unroll
            for (int bb2 = 0; bb2 < 4; ++bb2) {
                float d2 = fmaf(v[w4 * 4 + bb2], -2048.0f, pm2048);  // (pm - v)*2048
                d2 = fminf(fmaxf(d2, 0.0f), 255.0f);
                unsigned q = (unsigned)d2;                            // floor
                wd |= q << (8 * bb2);
            }
            dw[(p << 2) + w4] = wd;
        }
        runmax = fmaxf(runmax, pm);
    }

    // ---- threshold: validated margin; rowmax exact (from f32 pm values)
    float rowmax = fmaxf(runmax, __shfl_xor(runmax, 32, 64));
    const float thr = rowmax - (sa * 1.7e-5f + 6.0e-4f);

    // ---- emission: scan stored deltas, O(candidates) LDS atomics
#pragma unroll
    for (int p = 0; p < 16; ++p) {
        float il = (pmv[p] - thr) * 2048.0f + 1.0f;   // +1 covers floor/FMA rounding
        if (il >= 0.0f) {
            unsigned ilu = (unsigned)il;
            const int cbase = (p << 5) + 4 * lh;
#pragma unroll
            for (int w4 = 0; w4 < 4; ++w4) {
                unsigned wd = dw[(p << 2) + w4];
#pragma unroll
                for (int bb2 = 0; bb2 < 4; ++bb2) {
                    unsigned q = (wd >> (8 * bb2)) & 255u;
                    if (q <= ilu) {
                        int i = w4 * 4 + bb2;
                        int code = cbase + (i & 3) + 8 * (i >> 2);
                        unsigned pos = atomicAdd(&cntl[row], 1u);
                        if (pos < 16u) candl[(row << 4) + pos] = (unsigned short)code;
                    }
                }
            }
        }
    }
    __syncthreads();

    if (t < 128) {
        unsigned c = cntl[t];
        if (c == 1u) idx_out[r0 + t] = (int)candl[t << 4];
        bool multi = (c >= 2u && c <= 16u);
        bool ofl   = (c > 16u);
        unsigned long long m = __ballot(multi);
        int lane = t & 63;
        int rank = __popcll(m & ((1ull << lane) - 1ull));
        int tot  = __popcll(m);
        unsigned base = 0;
        if (lane == 0 && tot) base = atomicAdd(&ctr[0], (unsigned)tot);
        base = __shfl(base, 0, 64);
        if (multi) mlist[base + rank] = (unsigned)(r0 + t) | (c << 16);
        if (ofl) {
            unsigned pos = atomicAdd(&ctr[1], 1u);
            if (pos < 65536u) oflist[pos] = (unsigned)(r0 + t);
        }
    }
    reinterpret_cast<uint4*>(codes_out + ((size_t)r0 << 4))[t] =
        reinterpret_cast<const uint4*>(candl)[t];
}

// ---------------- Pass 2: exact fp32 rescore via contiguous zt rows ----------------
__global__ __launch_bounds__(256) void vq_rescore2(const float* __restrict__ zt,
                                                   const float* __restrict__ cb,
                                                   const float* __restrict__ enb,
                                                   const float* __restrict__ znb,
                                                   const unsigned short* __restrict__ codes_in,
                                                   const unsigned* __restrict__ ctr,
                                                   const unsigned* __restrict__ mlist,
                                                   int* __restrict__ idx_out) {
    const unsigned N = ctr[0];
    const unsigned total = N * 2u;
    unsigned i = blockIdx.x * 256u + threadIdx.x;
    for (; i < total; i += gridDim.x * 256u) {
        unsigned e   = mlist[i >> 1];
        int side     = (int)(i & 1u);
        int row      = (int)(e & 0xFFFFu);
        int cnt      = (int)(e >> 16);
        const float* zp = zt + ((size_t)row << 8);
        const float  zn = znb[row];
        unsigned long long pk = 0xFFFFFFFFFFFFFFFFull;

        for (int j = side; j < cnt; j += 2) {
            int code = (int)codes_in[((size_t)row << 4) + j];
            const float* ep = cb + ((size_t)code << 8);
            float acc = 0.f;
#pragma unroll 8
            for (int u = 0; u < 64; ++u) {
                float4 zv = *reinterpret_cast<const float4*>(zp + (u << 2));
                float4 ev = *reinterpret_cast<const float4*>(ep + (u << 2));
                acc += zv.x * ev.x;   // sequential fp32 FMA chain
                acc += zv.y * ev.y;   // (identical order to validated kernel)
                acc += zv.z * ev.z;
                acc += zv.w * ev.w;
            }
            float d = (zn - 2.0f * acc) + enb[code];
            unsigned long long q =
                (((unsigned long long)__float_as_uint(d)) << 32) | (unsigned)code;
            if (q < pk) pk = q;
        }
        unsigned long long q2 = __shfl_xor(pk, 1, 64);
        if (q2 < pk) pk = q2;
        if (side == 0) idx_out[row] = (int)(unsigned)(pk & 0xFFFFFFFFu);
    }
}

// ---------------- Overflow rows: block per 4 rows, thread=code, coalesced cbT ----------------
__global__ __launch_bounds__(512) void vq_rescore_of(const float* __restrict__ zt,
                                                     const float* __restrict__ cbT,
                                                     const float* __restrict__ enb,
                                                     const float* __restrict__ znb,
                                                     const unsigned* __restrict__ ctr,
                                                     const unsigned* __restrict__ oflist,
                                                     int* __restrict__ idx_out) {
    __shared__ __align__(16) float zl[4][CDIM];
    __shared__ unsigned long long wmin[4][8];
    unsigned n = ctr[1]; if (n > 65536u) n = 65536u;
    const int t = threadIdx.x;
    const float en_t = enb[t];

    for (unsigned e0 = blockIdx.x << 2; e0 < n; e0 += gridDim.x << 2) {
        int nr = (int)(n - e0); if (nr > 4) nr = 4;
        if (t < (nr << 6)) {
            int slot = t >> 6, f = t & 63;
            int row = (int)oflist[e0 + slot];
            float4 v = *reinterpret_cast<const float4*>(zt + ((size_t)row << 8) + (f << 2));
            *reinterpret_cast<float4*>(&zl[slot][f << 2]) = v;
        }
        __syncthreads();

        float a0 = 0.f, a1 = 0.f, a2 = 0.f, a3 = 0.f;
#pragma unroll 8
        for (int c = 0; c < CDIM; ++c) {
            float ev = cbT[((size_t)c << 9) + t];    // coalesced column read
            a0 += zl[0][c] * ev;   // each chain: ascending-c sequential FMA
            a1 += zl[1][c] * ev;   // (identical per-chain order to validated kernel)
            a2 += zl[2][c] * ev;
            a3 += zl[3][c] * ev;
        }
        float accv[4] = {a0, a1, a2, a3};

        for (int slot = 0; slot < nr; ++slot) {
            int row = (int)oflist[e0 + slot];
            float d = (znb[row] - 2.0f * accv[slot]) + en_t;
            unsigned long long pk =
                (((unsigned long long)__float_as_uint(d)) << 32) | (unsigned)t;
#pragma unroll
            for (int o = 1; o < 64; o <<= 1) {
                unsigned long long q2 = __shfl_xor(pk, o, 64);
                if (q2 < pk) pk = q2;
            }
            if ((t & 63) == 0) wmin[slot][t >> 6] = pk;
        }
        __syncthreads();
        if (t < nr) {
            unsigned long long best = wmin[t][0];
#pragma unroll
            for (int i = 1; i < 8; ++i) if (wmin[t][i] < best) best = wmin[t][i];
            idx_out[(int)oflist[e0 + t]] = (int)(unsigned)(best & 0xFFFFFFFFu);
        }
        __syncthreads();
    }
}

// ---------------- Fallback exact kernels (validated round-2 path) ----------------
__global__ __launch_bounds__(64) void vq_enorm(const float* __restrict__ cb,
                                               float* __restrict__ enorm) {
    int k = blockIdx.x;
    int l = threadIdx.x;
    float4 v = *reinterpret_cast<const float4*>(cb + (size_t)k * CDIM + l * 4);
    float s = (v.x * v.x + v.y * v.y) + (v.z * v.z + v.w * v.w);
#pragma unroll
    for (int off = 1; off < 64; off <<= 1) s += __shfl_xor(s, off, 64);
    if (l == 0) enorm[k] = s;
}

__global__ __launch_bounds__(512) void vq_argmin(const float* __restrict__ z,
                                                 const float* __restrict__ cb,
                                                 const float* __restrict__ enorm,
                                                 int* __restrict__ out_idx) {
    __shared__ float zs[64][SZ];
    __shared__ float es[64][SZ];
    __shared__ float ens[K_CODES];
    __shared__ float zn[64];
    __shared__ float red_d[64][32];
    __shared__ int   red_i[64][32];

    const int t  = threadIdx.x;
    const int r0 = blockIdx.x * 64;
    const int b  = r0 >> 10;
    const int n0 = r0 & 1023;
    const float* zb = z + (size_t)b * CDIM * HW;

#pragma unroll
    for (int p = 0; p < 8; ++p) {
        int lin = p * 512 + t;
        int c   = lin >> 4;
        int i0  = (lin & 15) << 2;
        float4 v = *reinterpret_cast<const float4*>(zb + (size_t)c * HW + n0 + i0);
        zs[i0 + 0][c] = v.x; zs[i0 + 1][c] = v.y;
        zs[i0 + 2][c] = v.z; zs[i0 + 3][c] = v.w;
    }
    if (t < K_CODES) ens[t] = enorm[t];
    __syncthreads();

    if (t < 64) {
        float s0 = 0.f, s1 = 0.f, s2 = 0.f, s3 = 0.f;
        for (int c = 0; c < CDIM; c += 4) {
            float4 v = *reinterpret_cast<const float4*>(&zs[t][c]);
            s0 += v.x * v.x; s1 += v.y * v.y; s2 += v.z * v.z; s3 += v.w * v.w;
        }
        zn[t] = (s0 + s1) + (s2 + s3);
    }

    const int ty = t >> 5, tx = t & 31, row0 = ty * 4;
    float best_d[4]; int best_i[4];
#pragma unroll
    for (int i = 0; i < 4; ++i) { best_d[i] = 3.4e38f; best_i[i] = 0; }

    for (int K0 = 0; K0 < K_CODES; K0 += 64) {
        __syncthreads();
#pragma unroll
        for (int p = 0; p < 8; ++p) {
            int lin = p * 512 + t;
            int j = lin >> 6, c4 = (lin & 63) << 2;
            *reinterpret_cast<float4*>(&es[j][c4]) =
                *reinterpret_cast<const float4*>(cb + (size_t)(K0 + j) * CDIM + c4);
        }
        __syncthreads();

        float acc[4][2];
#pragma unroll
        for (int i = 0; i < 4; ++i) { acc[i][0] = 0.f; acc[i][1] = 0.f; }
#pragma unroll 4
        for (int k = 0; k < CDIM; k += 4) {
            float4 a0 = *reinterpret_cast<const float4*>(&zs[row0 + 0][k]);
            float4 a1 = *reinterpret_cast<const float4*>(&zs[row0 + 1][k]);
            float4 a2 = *reinterpret_cast<const float4*>(&zs[row0 + 2][k]);
            float4 a3 = *reinterpret_cast<const float4*>(&zs[row0 + 3][k]);
            float4 e0 = *reinterpret_cast<const float4*>(&es[tx][k]);
            float4 e1 = *reinterpret_cast<const float4*>(&es[tx + 32][k]);
            float4 aa[4] = {a0, a1, a2, a3};
#pragma unroll
            for (int i = 0; i < 4; ++i) {
#pragma unroll
                for (int j = 0; j < 2; ++j) {
                    float4 e = j ? e1 : e0;
                    acc[i][j] += aa[i].x * e.x; acc[i][j] += aa[i].y * e.y;
                    acc[i][j] += aa[i].z * e.z; acc[i][j] += aa[i].w * e.w;
                }
            }
        }
#pragma unroll
        for (int i = 0; i < 4; ++i) {
            float zni = zn[row0 + i];
#pragma unroll
            for (int j = 0; j < 2; ++j) {
                int code = K0 + j * 32 + tx;
                float d = (zni - 2.0f * acc[i][j]) + ens[code];
                if (d < best_d[i]) { best_d[i] = d; best_i[i] = code; }
            }
        }
    }
    __syncthreads();
#pragma unroll
    for (int i = 0; i < 4; ++i) {
        red_d[row0 + i][tx] = best_d[i];
        red_i[row0 + i][tx] = best_i[i];
    }
    __syncthreads();
    if (t < 64) {
        float bd = red_d[t][0]; int bi = red_i[t][0];
        for (int x = 1; x < 32; ++x) {
            float d = red_d[t][x]; int ii = red_i[t][x];
            if (d < bd || (d == bd && ii < bi)) { bd = d; bi = ii; }
        }
        out_idx[r0 + t] = bi;
    }
}

// ---------------- Gather: float4 stores, 1024 blocks ----------------
__global__ __launch_bounds__(256) void vq_gather(const float* __restrict__ cb,
                                                 const int* __restrict__ idx,
                                                 float* __restrict__ out) {
    const int blk = blockIdx.x;
    const int b = blk >> 4;
    const int q = blk & 15;
    const int t = threadIdx.x;
    int4 cd = reinterpret_cast<const int4*>(idx + (b << 10))[t];
    if (q == 0) {
        float4 f = make_float4((float)cd.x, (float)cd.y, (float)cd.z, (float)cd.w);
        reinterpret_cast<float4*>(out + (size_t)NBATCH * CDIM * HW + ((size_t)b << 10))[t] = f;
    }
    const int c0 = q << 4;
    const float* e0 = cb + (size_t)cd.x * CDIM + c0;
    const float* e1 = cb + (size_t)cd.y * CDIM + c0;
    const float* e2 = cb + (size_t)cd.z * CDIM + c0;
    const float* e3 = cb + (size_t)cd.w * CDIM + c0;
    float* ob = out + ((size_t)b * CDIM + c0) * HW + (t << 2);
#pragma unroll 4
    for (int c = 0; c < 16; ++c) {
        float4 v = make_float4(e0[c], e1[c], e2[c], e3[c]);
        *reinterpret_cast<float4*>(ob) = v;
        ob += HW;
    }
}

extern "C" void kernel_launch(void* const* d_in, const int* in_sizes, int n_in,
                              void* d_out, int out_size, void* d_ws, size_t ws_size,
                              hipStream_t stream) {
    const float* z  = (const float*)d_in[0];
    const float* cb = (const float*)d_in[1];
    float* out = (float*)d_out;
    float* zt  = (float*)d_out;   // z_q region (64 MiB) used as scratch, overwritten by gather

    // ws layout
    int*            idx   = (int*)d_ws;                                  // 262144 B
    float*          en    = (float*)((char*)d_ws + 262144);              // 2048 B
    unsigned short* cb16  = (unsigned short*)((char*)d_ws + 264192);     // 262144 B
    float*          znb   = (float*)((char*)d_ws + 526336);              // 262144 B
    unsigned short* codes = (unsigned short*)((char*)d_ws + 788480);     // 2097152 B
    unsigned*       mlist = (unsigned*)((char*)d_ws + 2885632);          // 262144 B
    unsigned*       ctr   = (unsigned*)((char*)d_ws + 3147776);          // 16 B
    unsigned*       oflist= (unsigned*)((char*)d_ws + 3147792);          // 262144 B
    float*          cbT   = (float*)((char*)d_ws + 3409936);             // 524288 B
    const size_t NEED_FULL = 3934224;

    if (ws_size >= NEED_FULL) {
        vq_setup     <<<dim3(1184), dim3(256), 0, stream>>>(z, cb, znb, zt, en, cb16, cbT, ctr);
        vq_pass1     <<<dim3(512),  dim3(256), 0, stream>>>(z, cb16, codes, idx, mlist, oflist, ctr);
        vq_rescore2  <<<dim3(512),  dim3(256), 0, stream>>>(zt, cb, en, znb, codes, ctr, mlist, idx);
        vq_rescore_of<<<dim3(512),  dim3(512), 0, stream>>>(zt, cbT, en, znb, ctr, oflist, idx);
    } else {
        vq_enorm  <<<dim3(K_CODES), dim3(64),  0, stream>>>(cb, en);
        vq_argmin <<<dim3(1024),    dim3(512), 0, stream>>>(z, cb, en, idx);
    }
    vq_gather<<<dim3(1024), dim3(256), 0, stream>>>(cb, idx, out);
}